// Round 2
// baseline (296.446 us; speedup 1.0000x reference)
//
#include <hip/hip_runtime.h>
#include <math.h>

// LDS layout (floats). Regions deliberately overlaid across phases:
//   [0,8192)      : C01 weight cache (stage A)  -> z1 quarter (16 planes x 512)
//                   -> z3 (256 planes x 10)      -> layer2/3 buffers
//   [8192,12800)  : z2 (64 planes x 72, padded for conflict-free core3 reads)
//   [12800,14848) : h1 (2048, layer-1 output w/ bias+ReLU)
#define OFF_Z1  0
#define OFF_Z2  8192
#define OFF_Z3  0
#define OFF_H1  12800
#define OFF_C01 0
#define OFF_L2A 0      // z21: 8 planes x 256
#define OFF_L2B 2048   // z22: 16 planes x 64
#define OFF_L2C 3072   // z23: 32 planes x 16
#define OFF_L2D 3584   // z24: 64 planes x 4
#define OFF_H2  3840   // 64
#define OFF_L3A 3904   // z31: 4 planes x 16
#define OFF_L3B 3968   // z32: 8 planes x 8
#define OFF_L3C 4032   // z33: 16 planes x 4
#define OFF_L3D 4096   // z34: 32 planes x 2
#define OFF_H3  4160   // 32
#define LDS_FLOATS 14848  // 59392 B < 64 KB -> 2 WGs/CU possible

// Precompute merged core0*core1: C01[p=(n1*8+n2)][j=(m1*4+m2)*2+q2]
//   = sum_r l1c0[0,m1,n1,r] * l1c1[r,m2,n2,q2]
__global__ void tt_setup_c01(const float* __restrict__ g0,
                             const float* __restrict__ g1,
                             float* __restrict__ c01) {
    int i = blockIdx.x * 256 + threadIdx.x;
    if (i >= 1536) return;
    int p = i >> 6, j = i & 63;
    int n1 = p >> 3, n2 = p & 7;
    int m1 = j >> 3, m2 = (j >> 1) & 3, q2 = j & 1;
    float s = 0.f;
#pragma unroll
    for (int r = 0; r < 3; ++r)
        s = fmaf(g0[m1 * 9 + n1 * 3 + r], g1[((r * 4 + m2) * 8 + n2) * 2 + q2], s);
    c01[i] = s;
}

__global__ __launch_bounds__(512)
void tt_main(const float* __restrict__ x,  const float* __restrict__ c01,
             const float* __restrict__ g2, const float* __restrict__ g3,
             const float* __restrict__ g4, const float* __restrict__ b1,
             const float* __restrict__ u0, const float* __restrict__ u1,
             const float* __restrict__ u2, const float* __restrict__ u3,
             const float* __restrict__ u4, const float* __restrict__ b2,
             const float* __restrict__ v0, const float* __restrict__ v1,
             const float* __restrict__ v2, const float* __restrict__ v3,
             const float* __restrict__ v4, const float* __restrict__ b3,
             const float* __restrict__ Wm, const float* __restrict__ bl,
             float* __restrict__ out)
{
    __shared__ float smem[LDS_FLOATS];
    const int t = threadIdx.x;
    const int b = blockIdx.x;
    const float* xs = x + (size_t)b * 12288;

    // ---- prefetch x: thread t owns s1=(n3,n4,n5)=t; 24 coalesced loads ----
    float xr[24];
#pragma unroll
    for (int p = 0; p < 24; ++p) xr[p] = xs[p * 512 + t];

    // ---- cache C01 in LDS (broadcast-read, region reused by z1 later) ----
    for (int i = t; i < 1536; i += 512) smem[OFF_C01 + i] = c01[i];
    __syncthreads();

    // ---- stage A (merged cores 0+1): acc[(m1*4+m2)*2+q2] for s1 = t ----
    float acc[64];
#pragma unroll
    for (int j = 0; j < 64; ++j) acc[j] = 0.f;
#pragma unroll 4
    for (int p = 0; p < 24; ++p) {
        const float xv = xr[p];
#pragma unroll
        for (int j = 0; j < 64; ++j)
            acc[j] = fmaf(xv, smem[OFF_C01 + p * 64 + j], acc[j]);
    }
    __syncthreads();  // C01 reads done before z1 overwrites region

    const int wv = t >> 6;        // wave id: core2 (m1l,m2) combo
    const int uu = t & 63;        // (n4,n5)
    const int c3_n5 = t & 7, c3_m3 = (t >> 3) & 3, c3_m2 = (t >> 5) & 3, c3_m1l = (t >> 7) & 1;
    const int c4_m4 = t & 3, c4_m3 = (t >> 2) & 3, c4_m2 = (t >> 4) & 3, c4_m1l = (t >> 6) & 1;

    // ---- 4 rounds over m1 pairs: stage z1 quarter -> core2 -> core3 -> core4 ----
#pragma unroll
    for (int R = 0; R < 4; ++R) {
        // (a) z1 quarter: plane=(q2*2+m1l)*4+m2, inner = t (lane-consecutive)
#pragma unroll
        for (int m1l = 0; m1l < 2; ++m1l)
#pragma unroll
            for (int m2 = 0; m2 < 4; ++m2)
#pragma unroll
                for (int q2 = 0; q2 < 2; ++q2)
                    smem[OFF_Z1 + (((q2 * 2 + m1l) * 4 + m2) << 9) + t] =
                        acc[((2 * R + m1l) * 4 + m2) * 2 + q2];
        __syncthreads();

        // (b) core2 (contract q2,n3): all 512 threads, unit=(m1l,m2,u)
        {
            const int m1l = wv >> 2, m2 = wv & 3;
            float a2[8];
#pragma unroll
            for (int j = 0; j < 8; ++j) a2[j] = 0.f;
#pragma unroll
            for (int q2 = 0; q2 < 2; ++q2)
#pragma unroll
                for (int n3 = 0; n3 < 8; ++n3) {
                    const float zv =
                        smem[OFF_Z1 + (((q2 * 2 + m1l) * 4 + m2) << 9) + (n3 << 6) + uu];
#pragma unroll
                    for (int m3 = 0; m3 < 4; ++m3)
#pragma unroll
                        for (int q3 = 0; q3 < 2; ++q3)
                            a2[m3 * 2 + q3] = fmaf(zv, g2[((q2 * 4 + m3) * 8 + n3) * 2 + q3],
                                                   a2[m3 * 2 + q3]);
                }
#pragma unroll
            for (int m3 = 0; m3 < 4; ++m3)
#pragma unroll
                for (int q3 = 0; q3 < 2; ++q3)
                    smem[OFF_Z2 + (((q3 * 2 + m1l) * 4 + m2) * 4 + m3) * 72 + uu] =
                        a2[m3 * 2 + q3];
        }
        __syncthreads();

        // (c) core3 (contract q3,n4): t<256, unit=(m1l,m2,m3,n5)
        if (t < 256) {
            float a3[8];
#pragma unroll
            for (int j = 0; j < 8; ++j) a3[j] = 0.f;
#pragma unroll
            for (int q3 = 0; q3 < 2; ++q3)
#pragma unroll
                for (int n4 = 0; n4 < 8; ++n4) {
                    const float zv = smem[OFF_Z2 +
                        (((q3 * 2 + c3_m1l) * 4 + c3_m2) * 4 + c3_m3) * 72 + n4 * 8 + c3_n5];
#pragma unroll
                    for (int m4 = 0; m4 < 4; ++m4)
#pragma unroll
                        for (int q4 = 0; q4 < 2; ++q4)
                            a3[m4 * 2 + q4] = fmaf(zv, g3[((q3 * 4 + m4) * 8 + n4) * 2 + q4],
                                                   a3[m4 * 2 + q4]);
                }
#pragma unroll
            for (int m4 = 0; m4 < 4; ++m4)
#pragma unroll
                for (int q4 = 0; q4 < 2; ++q4)
                    smem[OFF_Z3 +
                         ((((q4 * 2 + c3_m1l) * 4 + c3_m2) * 4 + c3_m3) * 4 + m4) * 10 + c3_n5] =
                        a3[m4 * 2 + q4];
        }
        __syncthreads();

        // (d) core4 (contract q4,n5) + bias + ReLU -> h1: t<128, unit=(m1l,m2,m3,m4)
        if (t < 128) {
            float a4[4] = {0.f, 0.f, 0.f, 0.f};
#pragma unroll
            for (int q4 = 0; q4 < 2; ++q4)
#pragma unroll
                for (int n5 = 0; n5 < 8; ++n5) {
                    const float zv = smem[OFF_Z3 +
                        ((((q4 * 2 + c4_m1l) * 4 + c4_m2) * 4 + c4_m3) * 4 + c4_m4) * 10 + n5];
#pragma unroll
                    for (int m5 = 0; m5 < 4; ++m5)
                        a4[m5] = fmaf(zv, g4[(q4 * 4 + m5) * 8 + n5], a4[m5]);
                }
            const int m1 = 2 * R + c4_m1l;
            const int hbase = m1 * 256 + c4_m2 * 64 + c4_m3 * 16 + c4_m4 * 4;
#pragma unroll
            for (int m5 = 0; m5 < 4; ++m5)
                smem[OFF_H1 + hbase + m5] = fmaxf(a4[m5] + b1[hbase + m5], 0.f);
        }
        __syncthreads();
    }

    // ================= layer 2: h1(8,4,4,4,4) -> h2(4,2,2,2,2) =================
    if (t < 256) {  // c0: contract n1(8); s=t=(n2,n3,n4,n5)
        float a[8];
#pragma unroll
        for (int j = 0; j < 8; ++j) a[j] = 0.f;
#pragma unroll
        for (int n1 = 0; n1 < 8; ++n1) {
            const float hv = smem[OFF_H1 + n1 * 256 + t];
#pragma unroll
            for (int m1 = 0; m1 < 4; ++m1)
#pragma unroll
                for (int q = 0; q < 2; ++q)
                    a[m1 * 2 + q] = fmaf(hv, u0[(m1 * 8 + n1) * 2 + q], a[m1 * 2 + q]);
        }
#pragma unroll
        for (int m1 = 0; m1 < 4; ++m1)
#pragma unroll
            for (int q = 0; q < 2; ++q)
                smem[OFF_L2A + (q * 4 + m1) * 256 + t] = a[m1 * 2 + q];
    }
    __syncthreads();
    if (t < 256) {  // c1: contract q,n2(4); unit: m1=t&3, vv=t>>2 (n3n4n5)
        const int m1 = t & 3, vv = t >> 2;
        float a[4];
#pragma unroll
        for (int j = 0; j < 4; ++j) a[j] = 0.f;
#pragma unroll
        for (int q = 0; q < 2; ++q)
#pragma unroll
            for (int n2 = 0; n2 < 4; ++n2) {
                const float zv = smem[OFF_L2A + (q * 4 + m1) * 256 + n2 * 64 + vv];
#pragma unroll
                for (int m2 = 0; m2 < 2; ++m2)
#pragma unroll
                    for (int q2 = 0; q2 < 2; ++q2)
                        a[m2 * 2 + q2] = fmaf(zv, u1[((q * 2 + m2) * 4 + n2) * 2 + q2],
                                              a[m2 * 2 + q2]);
            }
#pragma unroll
        for (int m2 = 0; m2 < 2; ++m2)
#pragma unroll
            for (int q2 = 0; q2 < 2; ++q2)
                smem[OFF_L2B + ((q2 * 4 + m1) * 2 + m2) * 64 + vv] = a[m2 * 2 + q2];
    }
    __syncthreads();
    if (t < 128) {  // c2: contract q2,n3(4); unit: m2=t&1, m1=(t>>1)&3, vv2=t>>3 (n4n5)
        const int m2 = t & 1, m1 = (t >> 1) & 3, vv2 = t >> 3;
        float a[4];
#pragma unroll
        for (int j = 0; j < 4; ++j) a[j] = 0.f;
#pragma unroll
        for (int q2 = 0; q2 < 2; ++q2)
#pragma unroll
            for (int n3 = 0; n3 < 4; ++n3) {
                const float zv = smem[OFF_L2B + ((q2 * 4 + m1) * 2 + m2) * 64 + n3 * 16 + vv2];
#pragma unroll
                for (int m3 = 0; m3 < 2; ++m3)
#pragma unroll
                    for (int q3 = 0; q3 < 2; ++q3)
                        a[m3 * 2 + q3] = fmaf(zv, u2[((q2 * 2 + m3) * 4 + n3) * 2 + q3],
                                              a[m3 * 2 + q3]);
            }
#pragma unroll
        for (int m3 = 0; m3 < 2; ++m3)
#pragma unroll
            for (int q3 = 0; q3 < 2; ++q3)
                smem[OFF_L2C + (((q3 * 4 + m1) * 2 + m2) * 2 + m3) * 16 + vv2] = a[m3 * 2 + q3];
    }
    __syncthreads();
    if (t < 64) {  // c3: contract q3,n4(4); unit: m3=t&1,m2=(t>>1)&1,m1=(t>>2)&3,n5=(t>>4)&3
        const int m3 = t & 1, m2 = (t >> 1) & 1, m1 = (t >> 2) & 3, n5 = (t >> 4) & 3;
        float a[4];
#pragma unroll
        for (int j = 0; j < 4; ++j) a[j] = 0.f;
#pragma unroll
        for (int q3 = 0; q3 < 2; ++q3)
#pragma unroll
            for (int n4 = 0; n4 < 4; ++n4) {
                const float zv =
                    smem[OFF_L2C + (((q3 * 4 + m1) * 2 + m2) * 2 + m3) * 16 + n4 * 4 + n5];
#pragma unroll
                for (int m4 = 0; m4 < 2; ++m4)
#pragma unroll
                    for (int q4 = 0; q4 < 2; ++q4)
                        a[m4 * 2 + q4] = fmaf(zv, u3[((q3 * 2 + m4) * 4 + n4) * 2 + q4],
                                              a[m4 * 2 + q4]);
            }
#pragma unroll
        for (int m4 = 0; m4 < 2; ++m4)
#pragma unroll
            for (int q4 = 0; q4 < 2; ++q4)
                smem[OFF_L2D + ((((q4 * 4 + m1) * 2 + m2) * 2 + m3) * 2 + m4) * 4 + n5] =
                    a[m4 * 2 + q4];
    }
    __syncthreads();
    if (t < 32) {  // c4: contract q4,n5(4); unit: m4=t&1,m3=(t>>1)&1,m2=(t>>2)&1,m1=t>>3
        const int m4 = t & 1, m3 = (t >> 1) & 1, m2 = (t >> 2) & 1, m1 = t >> 3;
        float a[2] = {0.f, 0.f};
#pragma unroll
        for (int q4 = 0; q4 < 2; ++q4)
#pragma unroll
            for (int n5 = 0; n5 < 4; ++n5) {
                const float zv =
                    smem[OFF_L2D + ((((q4 * 4 + m1) * 2 + m2) * 2 + m3) * 2 + m4) * 4 + n5];
#pragma unroll
                for (int m5 = 0; m5 < 2; ++m5)
                    a[m5] = fmaf(zv, u4[(q4 * 2 + m5) * 4 + n5], a[m5]);
            }
        const int hb = m1 * 16 + m2 * 8 + m3 * 4 + m4 * 2;
#pragma unroll
        for (int m5 = 0; m5 < 2; ++m5)
            smem[OFF_H2 + hb + m5] = fmaxf(a[m5] + b2[hb + m5], 0.f);
    }
    __syncthreads();

    // ================= layer 3: h2(4,2,2,2,2) -> h3(2,2,2,2,2) =================
    if (t < 16) {  // c0: contract n1(4)
        float a[4];
#pragma unroll
        for (int j = 0; j < 4; ++j) a[j] = 0.f;
#pragma unroll
        for (int n1 = 0; n1 < 4; ++n1) {
            const float hv = smem[OFF_H2 + n1 * 16 + t];
#pragma unroll
            for (int m1 = 0; m1 < 2; ++m1)
#pragma unroll
                for (int q = 0; q < 2; ++q)
                    a[m1 * 2 + q] = fmaf(hv, v0[(m1 * 4 + n1) * 2 + q], a[m1 * 2 + q]);
        }
#pragma unroll
        for (int m1 = 0; m1 < 2; ++m1)
#pragma unroll
            for (int q = 0; q < 2; ++q)
                smem[OFF_L3A + (q * 2 + m1) * 16 + t] = a[m1 * 2 + q];
    }
    __syncthreads();
    if (t < 16) {  // c1: contract q,n2(2); m1=t&1, vv=t>>1
        const int m1 = t & 1, vv = t >> 1;
        float a[4];
#pragma unroll
        for (int j = 0; j < 4; ++j) a[j] = 0.f;
#pragma unroll
        for (int q = 0; q < 2; ++q)
#pragma unroll
            for (int n2 = 0; n2 < 2; ++n2) {
                const float zv = smem[OFF_L3A + (q * 2 + m1) * 16 + n2 * 8 + vv];
#pragma unroll
                for (int m2 = 0; m2 < 2; ++m2)
#pragma unroll
                    for (int q2 = 0; q2 < 2; ++q2)
                        a[m2 * 2 + q2] = fmaf(zv, v1[((q * 2 + m2) * 2 + n2) * 2 + q2],
                                              a[m2 * 2 + q2]);
            }
#pragma unroll
        for (int m2 = 0; m2 < 2; ++m2)
#pragma unroll
            for (int q2 = 0; q2 < 2; ++q2)
                smem[OFF_L3B + ((q2 * 2 + m1) * 2 + m2) * 8 + vv] = a[m2 * 2 + q2];
    }
    __syncthreads();
    if (t < 16) {  // c2: contract q2,n3(2); m2=t&1, m1=(t>>1)&1, vv2=t>>2
        const int m2 = t & 1, m1 = (t >> 1) & 1, vv2 = t >> 2;
        float a[4];
#pragma unroll
        for (int j = 0; j < 4; ++j) a[j] = 0.f;
#pragma unroll
        for (int q2 = 0; q2 < 2; ++q2)
#pragma unroll
            for (int n3 = 0; n3 < 2; ++n3) {
                const float zv = smem[OFF_L3B + ((q2 * 2 + m1) * 2 + m2) * 8 + n3 * 4 + vv2];
#pragma unroll
                for (int m3 = 0; m3 < 2; ++m3)
#pragma unroll
                    for (int q3 = 0; q3 < 2; ++q3)
                        a[m3 * 2 + q3] = fmaf(zv, v2[((q2 * 2 + m3) * 2 + n3) * 2 + q3],
                                              a[m3 * 2 + q3]);
            }
#pragma unroll
        for (int m3 = 0; m3 < 2; ++m3)
#pragma unroll
            for (int q3 = 0; q3 < 2; ++q3)
                smem[OFF_L3C + (((q3 * 2 + m1) * 2 + m2) * 2 + m3) * 4 + vv2] = a[m3 * 2 + q3];
    }
    __syncthreads();
    if (t < 16) {  // c3: contract q3,n4(2); m3=t&1,m2=(t>>1)&1,m1=(t>>2)&1,n5=(t>>3)&1
        const int m3 = t & 1, m2 = (t >> 1) & 1, m1 = (t >> 2) & 1, n5 = (t >> 3) & 1;
        float a[4];
#pragma unroll
        for (int j = 0; j < 4; ++j) a[j] = 0.f;
#pragma unroll
        for (int q3 = 0; q3 < 2; ++q3)
#pragma unroll
            for (int n4 = 0; n4 < 2; ++n4) {
                const float zv =
                    smem[OFF_L3C + (((q3 * 2 + m1) * 2 + m2) * 2 + m3) * 4 + n4 * 2 + n5];
#pragma unroll
                for (int m4 = 0; m4 < 2; ++m4)
#pragma unroll
                    for (int q4 = 0; q4 < 2; ++q4)
                        a[m4 * 2 + q4] = fmaf(zv, v3[((q3 * 2 + m4) * 2 + n4) * 2 + q4],
                                              a[m4 * 2 + q4]);
            }
#pragma unroll
        for (int m4 = 0; m4 < 2; ++m4)
#pragma unroll
            for (int q4 = 0; q4 < 2; ++q4)
                smem[OFF_L3D + ((((q4 * 2 + m1) * 2 + m2) * 2 + m3) * 2 + m4) * 2 + n5] =
                    a[m4 * 2 + q4];
    }
    __syncthreads();
    if (t < 16) {  // c4: contract q4,n5(2); unit=(m1..m4)=t, h3 idx = 2t+m5
        const int m4 = t & 1, m3 = (t >> 1) & 1, m2 = (t >> 2) & 1, m1 = (t >> 3) & 1;
        float a[2] = {0.f, 0.f};
#pragma unroll
        for (int q4 = 0; q4 < 2; ++q4)
#pragma unroll
            for (int n5 = 0; n5 < 2; ++n5) {
                const float zv =
                    smem[OFF_L3D + ((((q4 * 2 + m1) * 2 + m2) * 2 + m3) * 2 + m4) * 2 + n5];
#pragma unroll
                for (int m5 = 0; m5 < 2; ++m5)
                    a[m5] = fmaf(zv, v4[(q4 * 2 + m5) * 2 + n5], a[m5]);
            }
        const int hb = m1 * 16 + m2 * 8 + m3 * 4 + m4 * 2;
#pragma unroll
        for (int m5 = 0; m5 < 2; ++m5)
            smem[OFF_H3 + hb + m5] = fmaxf(a[m5] + b3[hb + m5], 0.f);
    }
    __syncthreads();

    // ================= head: logits + log_softmax =================
    if (t < 64) {
        const int c = t >> 5, k = t & 31;
        float pr = smem[OFF_H3 + k] * Wm[c * 32 + k];
#pragma unroll
        for (int d = 16; d >= 1; d >>= 1) pr += __shfl_xor(pr, d);
        const float l0 = __shfl(pr, 0) + bl[0];
        const float l1 = __shfl(pr, 32) + bl[1];
        if (t == 0) {
            const float mm = fmaxf(l0, l1);
            const float lse = mm + logf(expf(l0 - mm) + expf(l1 - mm));
            out[(size_t)b * 2 + 0] = l0 - lse;
            out[(size_t)b * 2 + 1] = l1 - lse;
        }
    }
}

extern "C" void kernel_launch(void* const* d_in, const int* in_sizes, int n_in,
                              void* d_out, int out_size, void* d_ws, size_t ws_size,
                              hipStream_t stream) {
    const float* x    = (const float*)d_in[0];
    const float* l1c0 = (const float*)d_in[1];
    const float* l1c1 = (const float*)d_in[2];
    const float* l1c2 = (const float*)d_in[3];
    const float* l1c3 = (const float*)d_in[4];
    const float* l1c4 = (const float*)d_in[5];
    const float* b1   = (const float*)d_in[6];
    const float* l2c0 = (const float*)d_in[7];
    const float* l2c1 = (const float*)d_in[8];
    const float* l2c2 = (const float*)d_in[9];
    const float* l2c3 = (const float*)d_in[10];
    const float* l2c4 = (const float*)d_in[11];
    const float* b2   = (const float*)d_in[12];
    const float* l3c0 = (const float*)d_in[13];
    const float* l3c1 = (const float*)d_in[14];
    const float* l3c2 = (const float*)d_in[15];
    const float* l3c3 = (const float*)d_in[16];
    const float* l3c4 = (const float*)d_in[17];
    const float* b3   = (const float*)d_in[18];
    const float* Wm   = (const float*)d_in[19];
    const float* bl   = (const float*)d_in[20];
    float* C01 = (float*)d_ws;  // 1536 floats scratch

    tt_setup_c01<<<6, 256, 0, stream>>>(l1c0, l1c1, C01);
    tt_main<<<2048, 512, 0, stream>>>(x, C01, l1c2, l1c3, l1c4, b1,
                                      l2c0, l2c1, l2c2, l2c3, l2c4, b2,
                                      l3c0, l3c1, l3c2, l3c3, l3c4, b3,
                                      Wm, bl, (float*)d_out);
}

// Round 3
// 220.872 us; speedup vs baseline: 1.3422x; 1.3422x over previous
//
#include <hip/hip_runtime.h>
#include <math.h>

// ---------------- LDS layout (floats) ----------------
// Weights (persistent):
#define LC4   0      // l1c4 [q4][m5][n5]                 (64)
#define LC3   64     // l1c3 [q3][m4][n4][q4]             (128)
#define LC2   192    // l1c2 [q2][m3][n3][q3]             (128)
#define LC1   320    // l1c1 [q1][m2][n2][q2]             (192)
#define LC0   512    // l1c0 [m1][n1][q1]                 (72)
#define LU4   584    // l2c4                              (16)
#define LU3   600    // l2c3                              (32)
#define LU2   632    // l2c2                              (32)
#define LU1   664    // l2c1                              (32)
#define LU0   696    // l2c0 [m1][n1][q1]                 (64)
#define LB2   760    // bias2                             (64)
#define LB3   824    // bias3                             (32)
#define LWH   856    // head W (2,32)                     (64)
#define LBL   920    // head bias                         (2) -> 922, pad to 924
#define LW3   924    // dense layer3 W3[32][64]           (2048) -> end 2972
// Buffers:
#define T2O   2972   // T2[prefix(192)][33]  (pad 33 -> conflict-free)  6336 -> 9308
#define T3O   9308   // T3[(nn*4+m3)(96)][33]                           3168 -> 12476
#define H1O   9308   // h1 (2048) overlays T3 (T3 dead after step4)
#define T4O   2972   // T4[j(256)][9] overlays T2 (dead after step3)
#define L2AO  2972   // A[P(512)][5]   2560
#define L2BO  5532   // B[p3(128)][9]  1152
#define L2CO  6684   // C[p2(32)][17]   544
#define L2DO  7228   // D[s(16)][17]    272
#define H2O   7500   // h2 (64)
#define H3O   7564   // h3 (32)
#define LDS_FLOATS 12476   // 49,904 B -> 3 blocks/CU

// Setup: dense layer-3 matrix W3[mi(32)][nj(64)] from TT cores (tiny).
__global__ void tt_setup_w3(const float* __restrict__ v0, const float* __restrict__ v1,
                            const float* __restrict__ v2, const float* __restrict__ v3,
                            const float* __restrict__ v4, float* __restrict__ w3) {
    int i = blockIdx.x * 256 + threadIdx.x;
    if (i >= 2048) return;
    int mi = i >> 6, nj = i & 63;
    int m1 = (mi >> 4) & 1, m2 = (mi >> 3) & 1, m3 = (mi >> 2) & 1, m4 = (mi >> 1) & 1, m5 = mi & 1;
    int n1 = (nj >> 4) & 3, n2 = (nj >> 3) & 1, n3 = (nj >> 2) & 1, n4 = (nj >> 1) & 1, n5 = nj & 1;
    float s = 0.f;
#pragma unroll
    for (int q1 = 0; q1 < 2; ++q1) {
        float a1 = v0[(m1 * 4 + n1) * 2 + q1];
#pragma unroll
        for (int q2 = 0; q2 < 2; ++q2) {
            float a2 = a1 * v1[((q1 * 2 + m2) * 2 + n2) * 2 + q2];
#pragma unroll
            for (int q3 = 0; q3 < 2; ++q3) {
                float a3 = a2 * v2[((q2 * 2 + m3) * 2 + n3) * 2 + q3];
#pragma unroll
                for (int q4 = 0; q4 < 2; ++q4)
                    s = fmaf(a3 * v3[((q3 * 2 + m4) * 2 + n4) * 2 + q4],
                             v4[(q4 * 2 + m5) * 2 + n5], s);
            }
        }
    }
    w3[i] = s;
}

__global__ __launch_bounds__(192)
void tt_main(const float* __restrict__ x,
             const float* __restrict__ g0, const float* __restrict__ g1,
             const float* __restrict__ g2, const float* __restrict__ g3,
             const float* __restrict__ g4, const float* __restrict__ b1g,
             const float* __restrict__ u0, const float* __restrict__ u1,
             const float* __restrict__ u2, const float* __restrict__ u3,
             const float* __restrict__ u4, const float* __restrict__ b2g,
             const float* __restrict__ b3g,
             const float* __restrict__ Wmg, const float* __restrict__ blg,
             const float* __restrict__ w3g,
             float* __restrict__ out)
{
    __shared__ float smem[LDS_FLOATS];
    const int t = threadIdx.x;
    const int b = blockIdx.x;

    // ---- weight preload ----
    if (t < 64)  smem[LC4 + t] = g4[t];
    if (t < 128) smem[LC3 + t] = g3[t];
    if (t < 128) smem[LC2 + t] = g2[t];
    smem[LC1 + t] = g1[t];                 // exactly 192
    if (t < 72)  smem[LC0 + t] = g0[t];
    if (t < 16)  smem[LU4 + t] = u4[t];
    if (t < 32)  smem[LU3 + t] = u3[t];
    if (t < 32)  smem[LU2 + t] = u2[t];
    if (t < 32)  smem[LU1 + t] = u1[t];
    if (t < 64)  smem[LU0 + t] = u0[t];
    if (t < 64)  smem[LB2 + t] = b2g[t];
    if (t < 32)  smem[LB3 + t] = b3g[t];
    if (t < 64)  smem[LWH + t] = Wmg[t];
    if (t < 2)   smem[LBL + t] = blg[t];
#pragma unroll
    for (int i = t; i < 2048; i += 192) smem[LW3 + i] = w3g[i];

    // ---- phase A (steps 1+2 fused): x -> T2[prefix][m4,m5,q3] ----
    float accT2[32];
#pragma unroll
    for (int i = 0; i < 32; ++i) accT2[i] = 0.f;
    const float* xp = x + (size_t)b * 12288 + t * 64;

    __syncthreads();  // (1) weights ready

#pragma unroll
    for (int h = 0; h < 2; ++h) {  // n4 half: n4 = h*4 + n4l
        float xv[32];
        const float4* xp4 = (const float4*)(xp + h * 32);
#pragma unroll
        for (int i = 0; i < 8; ++i) {
            float4 v = xp4[i];
            xv[i * 4 + 0] = v.x; xv[i * 4 + 1] = v.y; xv[i * 4 + 2] = v.z; xv[i * 4 + 3] = v.w;
        }
        float t1[32];  // [(n4l*4+m5)*2+q4]
#pragma unroll
        for (int m5 = 0; m5 < 4; ++m5)
#pragma unroll
        for (int q4 = 0; q4 < 2; ++q4) {
            float w[8];
#pragma unroll
            for (int n5 = 0; n5 < 8; ++n5) w[n5] = smem[LC4 + (q4 * 4 + m5) * 8 + n5];
#pragma unroll
            for (int n4l = 0; n4l < 4; ++n4l) {
                float s = 0.f;
#pragma unroll
                for (int n5 = 0; n5 < 8; ++n5) s = fmaf(xv[n4l * 8 + n5], w[n5], s);
                t1[(n4l * 4 + m5) * 2 + q4] = s;
            }
        }
#pragma unroll
        for (int q3 = 0; q3 < 2; ++q3)
#pragma unroll
        for (int m4 = 0; m4 < 4; ++m4) {
            float cs[8];  // [n4l*2+q4]
#pragma unroll
            for (int k = 0; k < 8; ++k) cs[k] = smem[LC3 + ((q3 * 4 + m4) * 8 + h * 4) * 2 + k];
#pragma unroll
            for (int m5 = 0; m5 < 4; ++m5) {
                float s = accT2[(m4 * 4 + m5) * 2 + q3];
#pragma unroll
                for (int n4l = 0; n4l < 4; ++n4l)
#pragma unroll
                for (int q4 = 0; q4 < 2; ++q4)
                    s = fmaf(t1[(n4l * 4 + m5) * 2 + q4], cs[n4l * 2 + q4], s);
                accT2[(m4 * 4 + m5) * 2 + q3] = s;
            }
        }
    }
#pragma unroll
    for (int j = 0; j < 32; ++j) smem[T2O + t * 33 + j] = accT2[j];
    __syncthreads();  // (2) T2 ready

    // ---- step 3: contract n3,q3 -> T3[nn,m3][m4m5,q2] ----
    {
        const int q2 = t & 1, m3 = (t >> 1) & 3, nn = t >> 3;  // nn < 24
        float o3[16];
#pragma unroll
        for (int i = 0; i < 16; ++i) o3[i] = 0.f;
#pragma unroll
        for (int n3 = 0; n3 < 8; ++n3) {
            const int rb = T2O + (nn * 8 + n3) * 33;
            const float w0 = smem[LC2 + ((q2 * 4 + m3) * 8 + n3) * 2 + 0];
            const float w1 = smem[LC2 + ((q2 * 4 + m3) * 8 + n3) * 2 + 1];
#pragma unroll
            for (int m45 = 0; m45 < 16; ++m45) {
                const float z0 = smem[rb + m45 * 2 + 0];
                const float z1 = smem[rb + m45 * 2 + 1];
                o3[m45] = fmaf(z0, w0, fmaf(z1, w1, o3[m45]));
            }
        }
        const int wb = T3O + (nn * 4 + m3) * 33;
#pragma unroll
        for (int m45 = 0; m45 < 16; ++m45) smem[wb + m45 * 2 + q2] = o3[m45];
    }
    __syncthreads();  // (3) T3 ready (T2 dead)

    // ---- step 4: contract n2,q2 -> T4[j=(m2,m3,m4,m5)][n1*3+q1] ----
    {
        const int n1 = t >> 6, m2 = (t >> 4) & 3, m3 = (t >> 2) & 3, m4 = t & 3;
        float o4[12];  // [m5*3+q1]
#pragma unroll
        for (int i = 0; i < 12; ++i) o4[i] = 0.f;
#pragma unroll
        for (int n2 = 0; n2 < 8; ++n2) {
            float tv[8];  // [m5*2+q2]
            const int rb = T3O + ((n1 * 8 + n2) * 4 + m3) * 33 + m4 * 8;
#pragma unroll
            for (int k = 0; k < 8; ++k) tv[k] = smem[rb + k];
#pragma unroll
            for (int q2 = 0; q2 < 2; ++q2)
#pragma unroll
            for (int q1 = 0; q1 < 3; ++q1) {
                const float w = smem[LC1 + ((q1 * 4 + m2) * 8 + n2) * 2 + q2];
#pragma unroll
                for (int m5 = 0; m5 < 4; ++m5)
                    o4[m5 * 3 + q1] = fmaf(tv[m5 * 2 + q2], w, o4[m5 * 3 + q1]);
            }
        }
        const int bj = m2 * 64 + m3 * 16 + m4 * 4;
#pragma unroll
        for (int m5 = 0; m5 < 4; ++m5)
#pragma unroll
        for (int q1 = 0; q1 < 3; ++q1)
            smem[T4O + (bj + m5) * 9 + n1 * 3 + q1] = o4[m5 * 3 + q1];
    }
    __syncthreads();  // (4) T4 ready (T3 dead)

    // ---- step 5: contract n1,q1 + bias + relu -> h1[m1*256+j] ----
#pragma unroll
    for (int r = 0; r < 2; ++r) {
        const int j = t + r * 192;
        if (j < 256) {
            float o5[8];
#pragma unroll
            for (int i = 0; i < 8; ++i) o5[i] = 0.f;
#pragma unroll
            for (int n1 = 0; n1 < 3; ++n1)
#pragma unroll
            for (int q1 = 0; q1 < 3; ++q1) {
                const float tv = smem[T4O + j * 9 + n1 * 3 + q1];
#pragma unroll
                for (int m1 = 0; m1 < 8; ++m1)
                    o5[m1] = fmaf(tv, smem[LC0 + (m1 * 3 + n1) * 3 + q1], o5[m1]);
            }
#pragma unroll
            for (int m1 = 0; m1 < 8; ++m1)
                smem[H1O + m1 * 256 + j] = fmaxf(o5[m1] + b1g[m1 * 256 + j], 0.f);
        }
    }
    __syncthreads();  // (5) h1 ready (T4 dead)

    // ================= layer 2 (right-to-left) =================
    // L2a: contract n5(4) -> A[P(512)][m5*2+q4]
#pragma unroll
    for (int r = 0; r < 3; ++r) {
        const int P = t + r * 192;
        if (P < 512) {
            float hv[4];
#pragma unroll
            for (int n5 = 0; n5 < 4; ++n5) hv[n5] = smem[H1O + P * 4 + n5];
#pragma unroll
            for (int m5 = 0; m5 < 2; ++m5)
#pragma unroll
            for (int q4 = 0; q4 < 2; ++q4) {
                float s = 0.f;
#pragma unroll
                for (int n5 = 0; n5 < 4; ++n5)
                    s = fmaf(hv[n5], smem[LU4 + (q4 * 2 + m5) * 4 + n5], s);
                smem[L2AO + P * 5 + m5 * 2 + q4] = s;
            }
        }
    }
    __syncthreads();  // (6)

    // L2b: contract n4(4),q4 -> B[p3(128)][(m4*2+m5)*2+q3]
    if (t < 128) {
        float o[8];
#pragma unroll
        for (int i = 0; i < 8; ++i) o[i] = 0.f;
#pragma unroll
        for (int n4 = 0; n4 < 4; ++n4)
#pragma unroll
        for (int q4 = 0; q4 < 2; ++q4) {
            const float a0 = smem[L2AO + (t * 4 + n4) * 5 + 0 * 2 + q4];
            const float a1 = smem[L2AO + (t * 4 + n4) * 5 + 1 * 2 + q4];
#pragma unroll
            for (int q3 = 0; q3 < 2; ++q3)
#pragma unroll
            for (int m4 = 0; m4 < 2; ++m4) {
                const float w = smem[LU3 + ((q3 * 2 + m4) * 4 + n4) * 2 + q4];
                o[(m4 * 2 + 0) * 2 + q3] = fmaf(a0, w, o[(m4 * 2 + 0) * 2 + q3]);
                o[(m4 * 2 + 1) * 2 + q3] = fmaf(a1, w, o[(m4 * 2 + 1) * 2 + q3]);
            }
        }
#pragma unroll
        for (int k = 0; k < 8; ++k) smem[L2BO + t * 9 + k] = o[k];
    }
    __syncthreads();  // (7)

    // L2c: contract n3(4),q3 -> C[p2(32)][(m3*4+m45)*2+q2]
    if (t < 32) {
        float o[16];
#pragma unroll
        for (int i = 0; i < 16; ++i) o[i] = 0.f;
#pragma unroll
        for (int n3 = 0; n3 < 4; ++n3)
#pragma unroll
        for (int q3 = 0; q3 < 2; ++q3) {
            float zb[4];
#pragma unroll
            for (int m45 = 0; m45 < 4; ++m45)
                zb[m45] = smem[L2BO + (t * 4 + n3) * 9 + m45 * 2 + q3];
#pragma unroll
            for (int m3 = 0; m3 < 2; ++m3)
#pragma unroll
            for (int q2 = 0; q2 < 2; ++q2) {
                const float w = smem[LU2 + ((q2 * 2 + m3) * 4 + n3) * 2 + q3];
#pragma unroll
                for (int m45 = 0; m45 < 4; ++m45)
                    o[(m3 * 4 + m45) * 2 + q2] = fmaf(zb[m45], w, o[(m3 * 4 + m45) * 2 + q2]);
            }
        }
#pragma unroll
        for (int k = 0; k < 16; ++k) smem[L2CO + t * 17 + k] = o[k];
    }
    __syncthreads();  // (8)

    // L2d: contract n2(4),q2 -> D[s(16)][n1*2+q1]
    if (t < 32) {
        const int n1 = t >> 2, m2 = (t >> 1) & 1, m3 = t & 1;
        float o[8];  // [m45*2+q1]
#pragma unroll
        for (int i = 0; i < 8; ++i) o[i] = 0.f;
#pragma unroll
        for (int n2 = 0; n2 < 4; ++n2)
#pragma unroll
        for (int q2 = 0; q2 < 2; ++q2) {
            float cb[4];
#pragma unroll
            for (int m45 = 0; m45 < 4; ++m45)
                cb[m45] = smem[L2CO + (n1 * 4 + n2) * 17 + (m3 * 4 + m45) * 2 + q2];
#pragma unroll
            for (int q1 = 0; q1 < 2; ++q1) {
                const float w = smem[LU1 + ((q1 * 2 + m2) * 4 + n2) * 2 + q2];
#pragma unroll
                for (int m45 = 0; m45 < 4; ++m45)
                    o[m45 * 2 + q1] = fmaf(cb[m45], w, o[m45 * 2 + q1]);
            }
        }
#pragma unroll
        for (int m45 = 0; m45 < 4; ++m45)
#pragma unroll
        for (int q1 = 0; q1 < 2; ++q1)
            smem[L2DO + (m2 * 8 + m3 * 4 + m45) * 17 + n1 * 2 + q1] = o[m45 * 2 + q1];
    }
    __syncthreads();  // (9)

    // L2e: contract n1(8),q1 + bias + relu -> h2[m1*16+s]
    if (t < 16) {
        float o[4];
#pragma unroll
        for (int i = 0; i < 4; ++i) o[i] = 0.f;
#pragma unroll
        for (int n1 = 0; n1 < 8; ++n1)
#pragma unroll
        for (int q1 = 0; q1 < 2; ++q1) {
            const float dv = smem[L2DO + t * 17 + n1 * 2 + q1];
#pragma unroll
            for (int m1 = 0; m1 < 4; ++m1)
                o[m1] = fmaf(dv, smem[LU0 + (m1 * 8 + n1) * 2 + q1], o[m1]);
        }
#pragma unroll
        for (int m1 = 0; m1 < 4; ++m1)
            smem[H2O + m1 * 16 + t] = fmaxf(o[m1] + smem[LB2 + m1 * 16 + t], 0.f);
    }
    __syncthreads();  // (10)

    // ---- layer 3 dense (W3 32x64) + relu ----
    if (t < 32) {
        float s = smem[LB3 + t];
#pragma unroll
        for (int k = 0; k < 64; ++k) {
            const int kk = (k + t) & 63;  // rotation: conflict-free, no pad needed
            s = fmaf(smem[LW3 + t * 64 + kk], smem[H2O + kk], s);
        }
        smem[H3O + t] = fmaxf(s, 0.f);
    }
    __syncthreads();  // (11)

    // ---- head: logits + log_softmax ----
    if (t < 64) {
        const int c = t >> 5, k = t & 31;
        float pr = smem[H3O + k] * smem[LWH + c * 32 + k];
#pragma unroll
        for (int d = 16; d >= 1; d >>= 1) pr += __shfl_xor(pr, d);
        const float l0 = __shfl(pr, 0) + smem[LBL + 0];
        const float l1 = __shfl(pr, 32) + smem[LBL + 1];
        if (t == 0) {
            const float mm = fmaxf(l0, l1);
            const float lse = mm + logf(expf(l0 - mm) + expf(l1 - mm));
            out[(size_t)b * 2 + 0] = l0 - lse;
            out[(size_t)b * 2 + 1] = l1 - lse;
        }
    }
}

extern "C" void kernel_launch(void* const* d_in, const int* in_sizes, int n_in,
                              void* d_out, int out_size, void* d_ws, size_t ws_size,
                              hipStream_t stream) {
    const float* x    = (const float*)d_in[0];
    const float* l1c0 = (const float*)d_in[1];
    const float* l1c1 = (const float*)d_in[2];
    const float* l1c2 = (const float*)d_in[3];
    const float* l1c3 = (const float*)d_in[4];
    const float* l1c4 = (const float*)d_in[5];
    const float* b1   = (const float*)d_in[6];
    const float* l2c0 = (const float*)d_in[7];
    const float* l2c1 = (const float*)d_in[8];
    const float* l2c2 = (const float*)d_in[9];
    const float* l2c3 = (const float*)d_in[10];
    const float* l2c4 = (const float*)d_in[11];
    const float* b2   = (const float*)d_in[12];
    const float* l3c0 = (const float*)d_in[13];
    const float* l3c1 = (const float*)d_in[14];
    const float* l3c2 = (const float*)d_in[15];
    const float* l3c3 = (const float*)d_in[16];
    const float* l3c4 = (const float*)d_in[17];
    const float* b3   = (const float*)d_in[18];
    const float* Wm   = (const float*)d_in[19];
    const float* bl   = (const float*)d_in[20];
    float* W3 = (float*)d_ws;  // 2048 floats scratch

    tt_setup_w3<<<8, 256, 0, stream>>>(l3c0, l3c1, l3c2, l3c3, l3c4, W3);
    tt_main<<<2048, 192, 0, stream>>>(x, l1c0, l1c1, l1c2, l1c3, l1c4, b1,
                                      l2c0, l2c1, l2c2, l2c3, l2c4, b2, b3,
                                      Wm, bl, W3, (float*)d_out);
}

// Round 4
// 209.117 us; speedup vs baseline: 1.4176x; 1.0562x over previous
//
#include <hip/hip_runtime.h>
#include <math.h>

// ---------------- LDS layout (floats), per 64-thread (1-wave) block ----------
#define WC3  0      // l1c3 [q3][m4][n4][q4]            128
#define WC2  128    // l1c2 [q2][m3][n3][q3]            128
#define WU1  256    // l2c1                              32  -> 288
#define T2S  288    // [32 prefixes][36]  (pad 36: b128-aligned rows)  1152 -> 1440
#define T3S  1440   // [32 rows][34]      (pad 34: b64-aligned)        1088 -> 2528
#define H1O  288    // h1 (2048) overlays T2S/T3S after layer-1 slices
#define AO   2528   // A[512][4] (float4 rows)           2048 -> 4576
#define BO   288    // B[128][9]                         1152 (overlays dead H1)
#define CO   1440   // C[32][17]                          544
#define DO   1984   // D[16][17]                          272
#define H2O  2256   // 64
#define H3O  2320   // 32 -> 2352
#define LDS_FLOATS 4576   // 18304 B -> 8 blocks/CU (one full residency round)

// Setup: dense layer-3 matrix W3[mi(32)][nj(64)] from TT cores (tiny).
__global__ void tt_setup_w3(const float* __restrict__ v0, const float* __restrict__ v1,
                            const float* __restrict__ v2, const float* __restrict__ v3,
                            const float* __restrict__ v4, float* __restrict__ w3) {
    int i = blockIdx.x * 256 + threadIdx.x;
    if (i >= 2048) return;
    int mi = i >> 6, nj = i & 63;
    int m1 = (mi >> 4) & 1, m2 = (mi >> 3) & 1, m3 = (mi >> 2) & 1, m4 = (mi >> 1) & 1, m5 = mi & 1;
    int n1 = (nj >> 4) & 3, n2 = (nj >> 3) & 1, n3 = (nj >> 2) & 1, n4 = (nj >> 1) & 1, n5 = nj & 1;
    float s = 0.f;
#pragma unroll
    for (int q1 = 0; q1 < 2; ++q1) {
        float a1 = v0[(m1 * 4 + n1) * 2 + q1];
#pragma unroll
        for (int q2 = 0; q2 < 2; ++q2) {
            float a2 = a1 * v1[((q1 * 2 + m2) * 2 + n2) * 2 + q2];
#pragma unroll
            for (int q3 = 0; q3 < 2; ++q3) {
                float a3 = a2 * v2[((q2 * 2 + m3) * 2 + n3) * 2 + q3];
#pragma unroll
                for (int q4 = 0; q4 < 2; ++q4)
                    s = fmaf(a3 * v3[((q3 * 2 + m4) * 2 + n4) * 2 + q4],
                             v4[(q4 * 2 + m5) * 2 + n5], s);
            }
        }
    }
    w3[i] = s;
}

__global__ __launch_bounds__(64, 2)
void tt_main(const float* __restrict__ x,
             const float* __restrict__ g0, const float* __restrict__ g1,
             const float* __restrict__ g2, const float* __restrict__ g3,
             const float* __restrict__ g4, const float* __restrict__ b1g,
             const float* __restrict__ u0, const float* __restrict__ u1,
             const float* __restrict__ u2, const float* __restrict__ u3,
             const float* __restrict__ u4, const float* __restrict__ b2g,
             const float* __restrict__ b3g,
             const float* __restrict__ Wmg, const float* __restrict__ blg,
             const float* __restrict__ w3g,
             float* __restrict__ out)
{
    __shared__ float smem[LDS_FLOATS];
    const int t = threadIdx.x;
    const int b = blockIdx.x;
    const float* xb = x + (size_t)b * 12288;

    // ---- issue x loads for subslice 0 (lane t owns 32 contiguous floats) ----
    float xv[32];
    {
        const float4* xq = (const float4*)xb + t * 8;
#pragma unroll
        for (int i = 0; i < 8; ++i) {
            const float4 v = xq[i];
            xv[i*4+0] = v.x; xv[i*4+1] = v.y; xv[i*4+2] = v.z; xv[i*4+3] = v.w;
        }
    }

    // ---- non-uniformly-indexed weights to LDS ----
    smem[WC3 + t] = g3[t];  smem[WC3 + 64 + t] = g3[64 + t];
    smem[WC2 + t] = g2[t];  smem[WC2 + 64 + t] = g2[64 + t];
    if (t < 32) smem[WU1 + t] = u1[t];
    __syncthreads();  // weights ready

    const int h = t & 1;       // n4-half owned by this lane
    const int p = t >> 1;      // subslice-local prefix (n2l*8 + n3)

    float regT4[36];           // [m2(4)][n1(3)*3+q1(3)] accumulated across slices
#pragma unroll
    for (int i = 0; i < 36; ++i) regT4[i] = 0.f;

#pragma unroll
    for (int n1 = 0; n1 < 3; ++n1) {
#pragma unroll
        for (int n2h = 0; n2h < 2; ++n2h) {
            const int s = n1 * 2 + n2h;
            // prefetch next x slab
            float xn[32];
            if (s < 5) {
                const float4* xq = (const float4*)xb + (s + 1) * 512 + t * 8;
#pragma unroll
                for (int i = 0; i < 8; ++i) {
                    const float4 v = xq[i];
                    xn[i*4+0] = v.x; xn[i*4+1] = v.y; xn[i*4+2] = v.z; xn[i*4+3] = v.w;
                }
            }

            // ---- step 1: t1[n4l*8 + m5*2+q4] = sum_n5 x * C4  (C4 uniform: s_load)
            float t1[32];
#pragma unroll
            for (int m5 = 0; m5 < 4; ++m5)
#pragma unroll
            for (int q4 = 0; q4 < 2; ++q4) {
                const float* w = g4 + (q4 * 4 + m5) * 8;
#pragma unroll
                for (int n4l = 0; n4l < 4; ++n4l) {
                    float sa = xv[n4l*8+0] * w[0];
#pragma unroll
                    for (int n5 = 1; n5 < 8; ++n5) sa = fmaf(xv[n4l*8+n5], w[n5], sa);
                    t1[n4l*8 + m5*2 + q4] = sa;
                }
            }

            // ---- step 2: acc[m4*4+m5] (q3 = h), contract n4 (own half, then
            //      partner's half via shfl_xor) and q4
            float acc[16];
#pragma unroll
            for (int i = 0; i < 16; ++i) acc[i] = 0.f;
#pragma unroll
            for (int pass = 0; pass < 2; ++pass) {
                const int hh = (pass == 0) ? h : (1 - h);   // n4-half of current t1
                if (pass == 1) {
#pragma unroll
                    for (int i = 0; i < 32; ++i) t1[i] = __shfl_xor(t1[i], 1);
                }
#pragma unroll
                for (int m4 = 0; m4 < 4; ++m4) {
                    const int cbase = WC3 + ((h * 4 + m4) * 8 + hh * 4) * 2;  // q3 = h
                    const float4 c0 = *(const float4*)&smem[cbase];
                    const float4 c1 = *(const float4*)&smem[cbase + 4];
                    const float cs[8] = {c0.x, c0.y, c0.z, c0.w, c1.x, c1.y, c1.z, c1.w};
#pragma unroll
                    for (int m5 = 0; m5 < 4; ++m5) {
                        float sa = acc[m4*4+m5];
#pragma unroll
                        for (int n4l = 0; n4l < 4; ++n4l)
#pragma unroll
                        for (int q4 = 0; q4 < 2; ++q4)
                            sa = fmaf(t1[n4l*8 + m5*2 + q4], cs[n4l*2 + q4], sa);
                        acc[m4*4+m5] = sa;
                    }
                }
            }

            __syncthreads();   // prior readers of T2S/T3S done
#pragma unroll
            for (int m45 = 0; m45 < 16; ++m45)
                smem[T2S + p * 36 + m45 * 2 + h] = acc[m45];
            __syncthreads();   // T2s ready

            // ---- step 3: contract n3 (half per lane) & q3 -> T3 rows
            {
                const int n3h = t & 1;
                const int q2  = (t >> 1) & 1;
                const int m3  = (t >> 2) & 3;
                const int n2l = t >> 4;
                float o3[16];
#pragma unroll
                for (int i = 0; i < 16; ++i) o3[i] = 0.f;
#pragma unroll
                for (int n3l = 0; n3l < 4; ++n3l) {
                    const int rb = T2S + (n2l * 8 + n3h * 4 + n3l) * 36;
                    float rv[32];
#pragma unroll
                    for (int g = 0; g < 8; ++g) {
                        const float4 v = *(const float4*)&smem[rb + g * 4];
                        rv[g*4+0] = v.x; rv[g*4+1] = v.y; rv[g*4+2] = v.z; rv[g*4+3] = v.w;
                    }
                    const int wb = WC2 + ((q2 * 4 + m3) * 8 + n3h * 4 + n3l) * 2;
                    const float w0 = smem[wb], w1 = smem[wb + 1];
#pragma unroll
                    for (int m45 = 0; m45 < 16; ++m45)
                        o3[m45] = fmaf(rv[m45*2], w0, fmaf(rv[m45*2+1], w1, o3[m45]));
                }
#pragma unroll
                for (int k = 0; k < 16; ++k) o3[k] += __shfl_xor(o3[k], 1);
                const int row = n2h * 16 + n2l * 4 + m3;   // = n2*4 + m3
#pragma unroll
                for (int k = 0; k < 8; ++k) {
                    const float v = n3h ? o3[8 + k] : o3[k];
                    smem[T3S + row * 34 + (n3h * 8 + k) * 2 + q2] = v;
                }
            }
            if (s < 5) {
#pragma unroll
                for (int i = 0; i < 32; ++i) xv[i] = xn[i];
            }
        } // n2h
        __syncthreads();   // T3 complete for this n1

        // ---- step 4: contract n2,q2 -> regT4 (C1 uniform: s_load)
        {
            const int m3 = t >> 4, m4 = (t >> 2) & 3, m5 = t & 3;
            float2 zz[8];
#pragma unroll
            for (int n2 = 0; n2 < 8; ++n2)
                zz[n2] = *(const float2*)&smem[T3S + (n2 * 4 + m3) * 34 + (m4 * 4 + m5) * 2];
#pragma unroll
            for (int jj = 0; jj < 4; ++jj)
#pragma unroll
            for (int q1 = 0; q1 < 3; ++q1) {
                float sa = regT4[jj * 9 + n1 * 3 + q1];
#pragma unroll
                for (int n2g = 0; n2g < 4; ++n2g) {
                    const float4 w = *(const float4*)(g1 + ((q1 * 4 + jj) * 8 + n2g * 2) * 2);
                    sa = fmaf(zz[n2g*2].x,   w.x, sa);
                    sa = fmaf(zz[n2g*2].y,   w.y, sa);
                    sa = fmaf(zz[n2g*2+1].x, w.z, sa);
                    sa = fmaf(zz[n2g*2+1].y, w.w, sa);
                }
                regT4[jj * 9 + n1 * 3 + q1] = sa;
            }
        }
    } // n1
    __syncthreads();   // T3 reads done; H1 may overwrite T2S/T3S zone

    // ---- step 5: contract n1,q1 + bias + relu -> h1 (C0 uniform: s_load)
#pragma unroll
    for (int jj = 0; jj < 4; ++jj) {
        float bia[8];
#pragma unroll
        for (int m1 = 0; m1 < 8; ++m1) bia[m1] = b1g[m1 * 256 + jj * 64 + t];
#pragma unroll
        for (int m1 = 0; m1 < 8; ++m1) {
            float sa = bia[m1];
#pragma unroll
            for (int n1 = 0; n1 < 3; ++n1)
#pragma unroll
            for (int q1 = 0; q1 < 3; ++q1)
                sa = fmaf(regT4[jj * 9 + n1 * 3 + q1], g0[(m1 * 3 + n1) * 3 + q1], sa);
            smem[H1O + m1 * 256 + jj * 64 + t] = fmaxf(sa, 0.f);
        }
    }
    __syncthreads();

    // ================= layer 2 (right-to-left) =================
    // L2a: contract n5(4) -> A[P][m5*2+q4] (float4 rows; U4 uniform)
#pragma unroll
    for (int pp = 0; pp < 8; ++pp) {
        const int P = pp * 64 + t;
        const float4 hv = *(const float4*)&smem[H1O + P * 4];
        float4 av;
        av.x = hv.x*u4[0]  + hv.y*u4[1]  + hv.z*u4[2]  + hv.w*u4[3];   // m5=0,q4=0
        av.y = hv.x*u4[8]  + hv.y*u4[9]  + hv.z*u4[10] + hv.w*u4[11];  // m5=0,q4=1
        av.z = hv.x*u4[4]  + hv.y*u4[5]  + hv.z*u4[6]  + hv.w*u4[7];   // m5=1,q4=0
        av.w = hv.x*u4[12] + hv.y*u4[13] + hv.z*u4[14] + hv.w*u4[15];  // m5=1,q4=1
        *(float4*)&smem[AO + P * 4] = av;
    }
    __syncthreads();

    // L2b: contract n4(4),q4 -> B[p3][(m4*2+m5)*2+q3]  (U3 uniform)
#pragma unroll
    for (int pp = 0; pp < 2; ++pp) {
        const int p3 = pp * 64 + t;
        float4 aa[4];
#pragma unroll
        for (int n4 = 0; n4 < 4; ++n4)
            aa[n4] = *(const float4*)&smem[AO + (p3 * 4 + n4) * 4];
        float o[8];
#pragma unroll
        for (int i = 0; i < 8; ++i) o[i] = 0.f;
#pragma unroll
        for (int n4 = 0; n4 < 4; ++n4)
#pragma unroll
        for (int q4 = 0; q4 < 2; ++q4) {
            const float a0 = q4 ? aa[n4].y : aa[n4].x;   // m5=0
            const float a1 = q4 ? aa[n4].w : aa[n4].z;   // m5=1
#pragma unroll
            for (int q3 = 0; q3 < 2; ++q3)
#pragma unroll
            for (int m4 = 0; m4 < 2; ++m4) {
                const float w = u3[((q3 * 2 + m4) * 4 + n4) * 2 + q4];
                o[(m4 * 2 + 0) * 2 + q3] = fmaf(a0, w, o[(m4 * 2 + 0) * 2 + q3]);
                o[(m4 * 2 + 1) * 2 + q3] = fmaf(a1, w, o[(m4 * 2 + 1) * 2 + q3]);
            }
        }
#pragma unroll
        for (int k = 0; k < 8; ++k) smem[BO + p3 * 9 + k] = o[k];
    }
    __syncthreads();

    // L2c: contract n3(4),q3 -> C[p2][(m3*4+m45)*2+q2]  (U2 uniform)
    if (t < 32) {
        float o[16];
#pragma unroll
        for (int i = 0; i < 16; ++i) o[i] = 0.f;
#pragma unroll
        for (int n3 = 0; n3 < 4; ++n3)
#pragma unroll
        for (int q3 = 0; q3 < 2; ++q3) {
            float zb[4];
#pragma unroll
            for (int m45 = 0; m45 < 4; ++m45)
                zb[m45] = smem[BO + (t * 4 + n3) * 9 + m45 * 2 + q3];
#pragma unroll
            for (int m3 = 0; m3 < 2; ++m3)
#pragma unroll
            for (int q2 = 0; q2 < 2; ++q2) {
                const float w = u2[((q2 * 2 + m3) * 4 + n3) * 2 + q3];
#pragma unroll
                for (int m45 = 0; m45 < 4; ++m45)
                    o[(m3 * 4 + m45) * 2 + q2] = fmaf(zb[m45], w, o[(m3 * 4 + m45) * 2 + q2]);
            }
        }
#pragma unroll
        for (int k = 0; k < 16; ++k) smem[CO + t * 17 + k] = o[k];
    }
    __syncthreads();

    // L2d: contract n2(4),q2 -> D[s][n1*2+q1]  (U1 non-uniform: LDS)
    if (t < 32) {
        const int n1 = t >> 2, m2 = (t >> 1) & 1, m3 = t & 1;
        float o[8];
#pragma unroll
        for (int i = 0; i < 8; ++i) o[i] = 0.f;
#pragma unroll
        for (int n2 = 0; n2 < 4; ++n2)
#pragma unroll
        for (int q2 = 0; q2 < 2; ++q2) {
            float cb[4];
#pragma unroll
            for (int m45 = 0; m45 < 4; ++m45)
                cb[m45] = smem[CO + (n1 * 4 + n2) * 17 + (m3 * 4 + m45) * 2 + q2];
#pragma unroll
            for (int q1 = 0; q1 < 2; ++q1) {
                const float w = smem[WU1 + ((q1 * 2 + m2) * 4 + n2) * 2 + q2];
#pragma unroll
                for (int m45 = 0; m45 < 4; ++m45)
                    o[m45 * 2 + q1] = fmaf(cb[m45], w, o[m45 * 2 + q1]);
            }
        }
#pragma unroll
        for (int m45 = 0; m45 < 4; ++m45)
#pragma unroll
        for (int q1 = 0; q1 < 2; ++q1)
            smem[DO + (m2 * 8 + m3 * 4 + m45) * 17 + n1 * 2 + q1] = o[m45 * 2 + q1];
    }
    __syncthreads();

    // L2e: contract n1(8),q1 + bias + relu -> h2  (U0 uniform)
    if (t < 16) {
        float o[4];
#pragma unroll
        for (int i = 0; i < 4; ++i) o[i] = 0.f;
#pragma unroll
        for (int n1 = 0; n1 < 8; ++n1)
#pragma unroll
        for (int q1 = 0; q1 < 2; ++q1) {
            const float dv = smem[DO + t * 17 + n1 * 2 + q1];
#pragma unroll
            for (int m1 = 0; m1 < 4; ++m1)
                o[m1] = fmaf(dv, u0[(m1 * 8 + n1) * 2 + q1], o[m1]);
        }
#pragma unroll
        for (int m1 = 0; m1 < 4; ++m1)
            smem[H2O + m1 * 16 + t] = fmaxf(o[m1] + b2g[m1 * 16 + t], 0.f);
    }
    __syncthreads();

    // ---- layer 3 dense (W3 32x64 from d_ws) + relu ----
    if (t < 32) {
        const float4* wr = (const float4*)(w3g + t * 64);
        float sa = b3g[t];
#pragma unroll
        for (int g = 0; g < 16; ++g) {
            const float4 w4 = wr[g];
            sa = fmaf(w4.x, smem[H2O + g*4 + 0],
                 fmaf(w4.y, smem[H2O + g*4 + 1],
                 fmaf(w4.z, smem[H2O + g*4 + 2],
                 fmaf(w4.w, smem[H2O + g*4 + 3], sa))));
        }
        smem[H3O + t] = fmaxf(sa, 0.f);
    }
    __syncthreads();

    // ---- head: logits + log_softmax ----
    {
        const int k = t & 31;
        float pr = smem[H3O + k] * Wmg[t];   // t = c*32 + k
#pragma unroll
        for (int d = 16; d >= 1; d >>= 1) pr += __shfl_xor(pr, d);
        const float l0 = __shfl(pr, 0) + blg[0];
        const float l1 = __shfl(pr, 32) + blg[1];
        if (t == 0) {
            const float mm = fmaxf(l0, l1);
            const float lse = mm + logf(expf(l0 - mm) + expf(l1 - mm));
            out[(size_t)b * 2 + 0] = l0 - lse;
            out[(size_t)b * 2 + 1] = l1 - lse;
        }
    }
}

extern "C" void kernel_launch(void* const* d_in, const int* in_sizes, int n_in,
                              void* d_out, int out_size, void* d_ws, size_t ws_size,
                              hipStream_t stream) {
    const float* x    = (const float*)d_in[0];
    const float* l1c0 = (const float*)d_in[1];
    const float* l1c1 = (const float*)d_in[2];
    const float* l1c2 = (const float*)d_in[3];
    const float* l1c3 = (const float*)d_in[4];
    const float* l1c4 = (const float*)d_in[5];
    const float* b1   = (const float*)d_in[6];
    const float* l2c0 = (const float*)d_in[7];
    const float* l2c1 = (const float*)d_in[8];
    const float* l2c2 = (const float*)d_in[9];
    const float* l2c3 = (const float*)d_in[10];
    const float* l2c4 = (const float*)d_in[11];
    const float* b2   = (const float*)d_in[12];
    const float* l3c0 = (const float*)d_in[13];
    const float* l3c1 = (const float*)d_in[14];
    const float* l3c2 = (const float*)d_in[15];
    const float* l3c3 = (const float*)d_in[16];
    const float* l3c4 = (const float*)d_in[17];
    const float* b3   = (const float*)d_in[18];
    const float* Wm   = (const float*)d_in[19];
    const float* bl   = (const float*)d_in[20];
    float* W3 = (float*)d_ws;  // 2048 floats scratch

    tt_setup_w3<<<8, 256, 0, stream>>>(l3c0, l3c1, l3c2, l3c3, l3c4, W3);
    tt_main<<<2048, 64, 0, stream>>>(x, l1c0, l1c1, l1c2, l1c3, l1c4, b1,
                                     l2c0, l2c1, l2c2, l2c3, l2c4, b2, b3,
                                     Wm, bl, W3, (float*)d_out);
}